// Round 2
// baseline (945.807 us; speedup 1.0000x reference)
//
#include <hip/hip_runtime.h>

// FilteredNoiseGenerator: B=32, t=4000, nbands=65, framesize=80, L_fir=129, L=208
// out[b, p] = sum over frames f, samples m: x[b,f,m]*w[b,f,tau], tau = (p+64) - 80f - m in [0,128]
// w[f][n] = hann[n] * zp[f][|n-64|], zp[f][d] = (2*sum_k H[f][k]cos(2pi k d/129) - H[f][0])/129

#define NT 256
#define NFRM 32            // frames per workgroup (4000 % 32 == 0 -> 125 groups)
#define H_STRIDE 68        // 65 + zero pad, multiple of 4
#define X_STRIDE 84        // 80 + pad; /4 = 21, odd mod 8 -> balanced b128 banking
#define W_STRIDE 164       // zero-padded w row; /4 = 41, odd mod 8 -> balanced b128 banking
#define W_P 16
#define OUT_PHYS 2864      // swizzled: max u = 2695, phys = u + (u>>4) = 2863

// P2 chunk schedule: 18 chunks (c covers d = 12c..12c+11), per-chunk step counts
// [3,6,9,12,15,18,20,20,20,20,20,19,16,13,10,7,4,1] partitioned into 8 groups of
// ~29 steps each; one group per half-wave (g = t>>5), frame = t&31.
// g0{6,2}=29 g1{7,14}=30 g2{8,16,0}=27 g3{10,1,17}=27 g4{9,15}=27 g5{11,3}=31 g6{5,13}=31 g7{12,4}=31
__constant__ int GCODE[8] = {
  6 | (2 << 8) | (255 << 16),
  7 | (14 << 8) | (255 << 16),
  8 | (16 << 8) | (0 << 16),
  10 | (1 << 8) | (17 << 16),
  9 | (15 << 8) | (255 << 16),
  11 | (3 << 8) | (255 << 16),
  5 | (13 << 8) | (255 << 16),
  12 | (4 << 8) | (255 << 16)
};

__global__ void __launch_bounds__(NT)
fng_kernel(const float* __restrict__ Hg_, const float* __restrict__ Ng_,
           float* __restrict__ Og_) {
  __shared__ __align__(16) float sH[NFRM * H_STRIDE];
  __shared__ __align__(16) float sW[NFRM * W_STRIDE];
  __shared__ __align__(16) float sX[NFRM * X_STRIDE];
  __shared__ __align__(16) float sO[OUT_PHYS];   // swizzled index: u + (u>>4)

  const int t  = threadIdx.x;
  const int bx = blockIdx.x;     // frame group 0..124
  const int b  = blockIdx.y;     // batch 0..31
  const int f0 = bx * NFRM;

  // ---------------- P0: zero LDS, stage H and x ----------------
  for (int i = t; i < NFRM * W_STRIDE; i += NT) sW[i] = 0.f;
  for (int i = t; i < OUT_PHYS; i += NT) sO[i] = 0.f;
  {
    const float* Hg = Hg_ + ((size_t)(b * 4000 + f0)) * 65;
    for (int i = t; i < NFRM * H_STRIDE; i += NT) {
      int fi = i / H_STRIDE, kk = i - fi * H_STRIDE;
      sH[i] = (kk < 65) ? Hg[fi * 65 + kk] : 0.f;
    }
    const float* Ng = Ng_ + (size_t)b * 320000 + (size_t)f0 * 80;
    for (int i = t; i < NFRM * 80; i += NT) {
      int fi = i / 80, m = i - fi * 80;
      sX[fi * X_STRIDE + m] = Ng[i] * 2.f - 1.f;   // noise in [0,1) -> [-1,1)
    }
  }
  __syncthreads();

  // ------- P1: zp via Chebyshev cos recurrence, write windowed FIR -------
  // Exactly 256 tasks: fi = t&31, db = t>>5 (8 blocks), d = 8*db + j, j in [0,9).
  // Covers d = 0..64 fully; d multiple of 8 computed twice -> identical-bit
  // duplicate LDS writes, benign. All threads equally loaded.
  {
    const int fi = t & 31;
    const int db = t >> 5;
    const float TP129 = 6.28318530717958647692f / 129.f;
    float two_a[9], cc[9], cm[9], acc[9];
#pragma unroll
    for (int j = 0; j < 9; ++j) {
      float a = __cosf((float)(8 * db + j) * TP129);
      two_a[j] = 2.f * a; cc[j] = 1.f; cm[j] = a; acc[j] = 0.f;
    }
    const float* hr = &sH[fi * H_STRIDE];
    const float h0 = hr[0];
    for (int k = 0; k < 68; k += 4) {          // k=65..67 are zero-padded
      float4 h4 = *(const float4*)&hr[k];
      const float hh[4] = {h4.x, h4.y, h4.z, h4.w};
#pragma unroll
      for (int mm = 0; mm < 4; ++mm) {
#pragma unroll
        for (int j = 0; j < 9; ++j) {
          acc[j] = fmaf(hh[mm], cc[j], acc[j]);
          float cn = fmaf(two_a[j], cc[j], -cm[j]);
          cm[j] = cc[j]; cc[j] = cn;
        }
      }
    }
    float* wr = &sW[fi * W_STRIDE];
#pragma unroll
    for (int j = 0; j < 9; ++j) {
      int d = 8 * db + j;                      // always <= 64
      float zp = (2.f * acc[j] - h0) * (1.f / 129.f);
      float hp = 0.5f - 0.5f * __cosf((float)(64 + d) * TP129);
      wr[W_P + 64 + d] = hp * zp;
      if (d > 0) {
        float hm = 0.5f - 0.5f * __cosf((float)(64 - d) * TP129);
        wr[W_P + 64 - d] = hm * zp;
      }
    }
  }
  __syncthreads();

  // ---------------- P2: convolution (scatter per frame into swizzled sO) ----------------
  auto conv_task = [&](int fi, int c) {
    const int d0 = 12 * c;                       // 0..204
    const int mlo = max(0, d0 - 128);            // multiple of 4
    const int m0hi = min(76, d0 + 8);
    const int nstep = ((m0hi - mlo) >> 2) + 1;   // >= 1 for all chunks
    const float* wr = &sW[fi * W_STRIDE];
    const float* xr = &sX[fi * X_STRIDE];
    float acc[12];
#pragma unroll
    for (int i = 0; i < 12; ++i) acc[i] = 0.f;
    int m0 = mlo;
    const int base = W_P + d0 - mlo;
    float4 qa = *(const float4*)&wr[base - 4];
    float4 qb = *(const float4*)&wr[base];
    float4 qc = *(const float4*)&wr[base + 4];
    float4 qd = *(const float4*)&wr[base + 8];
#pragma unroll 4
    for (int s = 0; s < nstep; ++s) {
      float4 x4 = *(const float4*)&xr[m0];
      const float xv[4] = {x4.x, x4.y, x4.z, x4.w};
      const float w16[16] = {qa.x, qa.y, qa.z, qa.w, qb.x, qb.y, qb.z, qb.w,
                             qc.x, qc.y, qc.z, qc.w, qd.x, qd.y, qd.z, qd.w};
#pragma unroll
      for (int mm = 0; mm < 4; ++mm)
#pragma unroll
        for (int i = 0; i < 12; ++i)
          acc[i] = fmaf(xv[mm], w16[4 + i - mm], acc[i]);  // rel in [1,15]
      m0 += 4;
      qd = qc; qc = qb; qb = qa;
      qa = *(const float4*)&wr[W_P + d0 - m0 - 4];  // >= 0 for all chunks
    }
    const int bu = 80 * fi + d0;
#pragma unroll
    for (int i = 0; i < 12; ++i) {
      int u = bu + i;
      atomicAdd(&sO[u + (u >> 4)], acc[i]);  // swizzle: lane stride 85 = 21 mod 32, all banks
    }
  };
  {
    const int g = t >> 5;
    const int fi = t & 31;
    unsigned code = (unsigned)GCODE[g];
#pragma unroll
    for (int kk = 0; kk < 3; ++kk) {
      int c = (code >> (8 * kk)) & 0xFF;
      if (c != 255) conv_task(fi, c);
    }
  }
  __syncthreads();

  // ---------------- P3: writeout (trim 64, overlap via atomics) ----------------
  {
    float* Ob = Og_ + (size_t)b * 320000;
    const int jb = 2560 * bx - 64;   // p = jb + u
    for (int u = t; u < 2688; u += NT) {
      int p = jb + u;
      if (p >= 0 && p < 320000) {
        float v = sO[u + (u >> 4)];
        if (u < 128 || u >= 2560) atomicAdd(&Ob[p], v);  // overlap with neighbor wg
        else Ob[p] = v;                                   // single writer
      }
    }
  }
}

extern "C" void kernel_launch(void* const* d_in, const int* in_sizes, int n_in,
                              void* d_out, int out_size, void* d_ws, size_t ws_size,
                              hipStream_t stream) {
  const float* H     = (const float*)d_in[0];   // [32,4000,65] fp32
  const float* noise = (const float*)d_in[1];   // [32,4000,80] fp32
  float* out = (float*)d_out;                   // [32,320000] fp32
  (void)in_sizes; (void)n_in; (void)d_ws; (void)ws_size;

  hipMemsetAsync(d_out, 0, (size_t)out_size * sizeof(float), stream);
  dim3 grid(125, 32, 1);
  fng_kernel<<<grid, NT, 0, stream>>>(H, noise, out);
}

// Round 3
// 555.361 us; speedup vs baseline: 1.7030x; 1.7030x over previous
//
#include <hip/hip_runtime.h>

// FilteredNoiseGenerator: B=32, t=4000, nbands=65, framesize=80, L_fir=129, L=208
// out[b,p] = sum_{f,m} x[b,f,m] * w[b,f,tau],  tau = (p+64) - 80f - m in [0,128]
// w[f][n] = hann[n]*zp[f][|n-64|],  zp[f][d] = (2*sum_k H[f][k]cos(2pi k d/129) - H[f][0])/129

#define NT 256
#define NFRM 16            // frames per workgroup; 4000/16 = 250 groups
#define H_STRIDE 68        // 65 + pad (zeros)
#define X_STRIDE 84        // 80 + pad (21 float4, rows 16B aligned)
#define W_STRIDE 164       // zero-padded w row; idx = W_P + tau, tau in [0,128]
#define W_P 16
#define SO_PHYS 1504       // swizzled accumulator: max u = 80*15+215 = 1415 -> phys 1503
#define SWZ(u) ((u) + ((u) >> 4))   // lane stride 80 -> phys 85 = 21 mod 32 (coprime)

// P2 schedule: 18 chunks (chunk c = outputs d in [12c,12c+12)), per-chunk m-step
// counts [3,6,9,12,15,18,20,20,20,20,20,19,16,13,10,7,4,1] (sum 233), chopped into
// 48 pieces of <=6 steps, packed 16 slots x 3 entries with column-uniform lengths
// (col maxima 6/5/5 -> lockstep wave cost 16 steps vs ideal 14.6).
// Encoding: (c<<10) | (s0<<5) | s1  (piece = steps [s0,s1) of chunk c).
__constant__ unsigned short SEG[3][16] = {
  {1030, 3078, 3276, 5126, 5324, 5522, 12294, 6149, 7173, 8197, 9221, 10245, 11269, 6314, 7338, 8362},
  {4101, 4266, 4431, 9386, 10410, 11434, 6479, 7503, 8527, 9551, 10575, 11599, 6644, 7668, 8692, 2053},
  {9716, 10740, 12491, 12656, 13317, 14341, 14506, 2217, 11763, 13481, 13613, 15364, 16388, 3, 15495, 17409}
};

__global__ void __launch_bounds__(NT, 6)   // spill guard: cap VGPR ~85 (R1 needed 76)
fng_kernel(const float* __restrict__ Hg_, const float* __restrict__ Ng_,
           float* __restrict__ Og_) {
  __shared__ __align__(16) float sH[NFRM * H_STRIDE];   // 4352 B
  __shared__ __align__(16) float sW[NFRM * W_STRIDE];   // 10496 B
  __shared__ __align__(16) float sX[NFRM * X_STRIDE];   // 5376 B
  __shared__ __align__(16) float sO[SO_PHYS];           // 6016 B  (total ~25.6 KB -> 6 WG/CU)

  const int t  = threadIdx.x;
  const int bx = blockIdx.x;     // frame group 0..249
  const int b  = blockIdx.y;     // batch 0..31
  const int f0 = bx * NFRM;
  const float TP = 6.28318530717958647692f / 129.f;

  // ---------------- P0: zero LDS, stage H and x ----------------
  {
    float4 z4 = {0.f, 0.f, 0.f, 0.f};
    for (int i = t; i < NFRM * W_STRIDE / 4; i += NT) ((float4*)sW)[i] = z4;
    for (int i = t; i < SO_PHYS / 4; i += NT) ((float4*)sO)[i] = z4;
    const float* Hg = Hg_ + ((size_t)(b * 4000 + f0)) * 65;
    for (int i = t; i < NFRM * H_STRIDE; i += NT) {
      int fi = i / H_STRIDE, kk = i - fi * H_STRIDE;
      sH[i] = (kk < 65) ? Hg[fi * 65 + kk] : 0.f;
    }
    const float4* Ng4 = (const float4*)(Ng_ + (size_t)b * 320000 + (size_t)f0 * 80);
    for (int i = t; i < NFRM * 20; i += NT) {        // 20 float4 per 80-sample frame
      int fi = i / 20, q = i - fi * 20;
      float4 v = Ng4[i];
      v.x = v.x * 2.f - 1.f; v.y = v.y * 2.f - 1.f;
      v.z = v.z * 2.f - 1.f; v.w = v.w * 2.f - 1.f;
      ((float4*)sX)[fi * 21 + q] = v;
    }
  }
  __syncthreads();

  // ------- P1: zp via Chebyshev cos recurrence, write windowed FIR -------
  // 256 tasks exactly: fi = t&15, dg = t>>4, chains d = dg + 16j (j<4) cover 0..63.
  {
    const int fi = t & 15;
    const int dg = t >> 4;
    float two_a[4], cc[4], cm[4], ac[4];
#pragma unroll
    for (int j = 0; j < 4; ++j) {
      float a = __cosf((float)(dg + 16 * j) * TP);
      two_a[j] = 2.f * a; cc[j] = 1.f; cm[j] = a; ac[j] = 0.f;
    }
    const float* hr = &sH[fi * H_STRIDE];
    const float h0 = hr[0];
#pragma unroll 1
    for (int k = 0; k < 68; k += 4) {                // k=65..67 zero-padded
      float4 h4 = *(const float4*)&hr[k];
      const float hh[4] = {h4.x, h4.y, h4.z, h4.w};
#pragma unroll
      for (int mm = 0; mm < 4; ++mm)
#pragma unroll
        for (int j = 0; j < 4; ++j) {
          ac[j] = fmaf(hh[mm], cc[j], ac[j]);
          float cn = fmaf(two_a[j], cc[j], -cm[j]);
          cm[j] = cc[j]; cc[j] = cn;
        }
    }
    float* wr = &sW[fi * W_STRIDE];
#pragma unroll
    for (int j = 0; j < 4; ++j) {
      int d = dg + 16 * j;                           // 0..63
      float zp = (2.f * ac[j] - h0) * (1.f / 129.f);
      wr[W_P + 64 + d] = (0.5f - 0.5f * __cosf((float)(64 + d) * TP)) * zp;
      wr[W_P + 64 - d] = (0.5f - 0.5f * __cosf((float)(64 - d) * TP)) * zp;
    }
    if (dg == 0) {                                   // d = 64 tail (wave 0 only, masked)
      const float a = __cosf(64.f * TP);
      float c_ = 1.f, cmv = a, a2 = 2.f * a, s_ = 0.f;
#pragma unroll 1
      for (int k = 0; k < 65; ++k) {
        s_ = fmaf(hr[k], c_, s_);
        float cn = fmaf(a2, c_, -cmv);
        cmv = c_; c_ = cn;
      }
      float zp = (2.f * s_ - h0) * (1.f / 129.f);
      wr[W_P + 128] = (0.5f - 0.5f * __cosf(128.f * TP)) * zp;
      // w[tau=0] = hann[0]*zp = 0: covered by sW zero-init.
    }
  }
  __syncthreads();

  // ------- P2: convolution pieces, scatter into swizzled sO via ds_add -------
  {
    const int fi = t & 15;
    const int slot = t >> 4;
    const float* wr = &sW[fi * W_STRIDE];
    const float* xr = &sX[fi * X_STRIDE];
#pragma unroll 1                                     // ONE conv-body copy (spill guard)
    for (int e = 0; e < 3; ++e) {
      const unsigned v = SEG[e][slot];
      const int c  = v >> 10;
      const int s0 = (v >> 5) & 31;
      const int s1 = v & 31;
      const int d0 = 12 * c;
      const int mlo = (d0 > 128) ? (d0 - 128) : 0;   // multiple of 4
      int m0 = mlo + 4 * s0;
      const int nstep = s1 - s0;                     // <= 6
      const int base = W_P + d0 - m0;                // base-4 >= 4, base+11 <= 155 (checked)
      float4 qa = *(const float4*)&wr[base - 4];
      float4 qb = *(const float4*)&wr[base];
      float4 qc = *(const float4*)&wr[base + 4];
      float4 qd = *(const float4*)&wr[base + 8];
      float acc[12];
#pragma unroll
      for (int i = 0; i < 12; ++i) acc[i] = 0.f;
#pragma unroll 1
      for (int s = 0; s < nstep; ++s) {
        float4 x4 = *(const float4*)&xr[m0];
        const float xv[4] = {x4.x, x4.y, x4.z, x4.w};
        const float w16[16] = {qa.x, qa.y, qa.z, qa.w, qb.x, qb.y, qb.z, qb.w,
                               qc.x, qc.y, qc.z, qc.w, qd.x, qd.y, qd.z, qd.w};
#pragma unroll
        for (int mm = 0; mm < 4; ++mm)
#pragma unroll
          for (int i = 0; i < 12; ++i)
            acc[i] = fmaf(xv[mm], w16[4 + i - mm], acc[i]);  // static idx in [1,15]
        m0 += 4;
        qd = qc; qc = qb; qb = qa;
        qa = *(const float4*)&wr[W_P + d0 - m0 - 4];  // proven >= 0 for all pieces
      }
      const int bu = 80 * fi + d0;
#pragma unroll
      for (int i = 0; i < 12; ++i) {
        int u = bu + i;
        atomicAdd(&sO[SWZ(u)], acc[i]);
      }
    }
  }
  __syncthreads();

  // ---------------- P3: writeout (trim 64, boundary overlap via atomics) ----------------
  {
    float* Ob = Og_ + (size_t)b * 320000;
    const int pb = 1280 * bx - 64;
    for (int u = t; u < 1408; u += NT) {
      int p = pb + u;
      if (p >= 0 && p < 320000) {
        float v = sO[SWZ(u)];
        if (u < 128 || u >= 1280) atomicAdd(&Ob[p], v);  // shared with neighbor WG
        else Ob[p] = v;                                   // single writer
      }
    }
  }
}

extern "C" void kernel_launch(void* const* d_in, const int* in_sizes, int n_in,
                              void* d_out, int out_size, void* d_ws, size_t ws_size,
                              hipStream_t stream) {
  const float* H     = (const float*)d_in[0];   // [32,4000,65] fp32
  const float* noise = (const float*)d_in[1];   // [32,4000,80] fp32
  float* out = (float*)d_out;                   // [32,320000] fp32
  (void)in_sizes; (void)n_in; (void)d_ws; (void)ws_size;

  hipMemsetAsync(d_out, 0, (size_t)out_size * sizeof(float), stream);
  dim3 grid(250, 32, 1);
  fng_kernel<<<grid, NT, 0, stream>>>(H, noise, out);
}

// Round 4
// 200.489 us; speedup vs baseline: 4.7175x; 2.7700x over previous
//
#include <hip/hip_runtime.h>

// FilteredNoiseGenerator: B=32, t=4000, nbands=65, framesize=80, L_fir=129, L=208
// out[b,p] = sum_{f,m} x[b,f,m]*w[b,f,tau], tau = (p+64) - 80f - m in [0,128]
// w[f][n] = hann[n]*zp[f][|n-64|], zp[f][d] = (2*sum_k H[f][k]cos(2pi k d/129) - H[f][0])/129
//
// GATHER form: workgroup owns 2560 outputs (32 frames); thread owns 10
// consecutive outputs u = 80*col + 10*pb + [0,10). For each of <=4 source
// frames g in {2,1,0,-1}: acc[i] += x[slot][m]*w[slot][dlt+i-m], iterated in
// m-quads with a 16-value register w-window (zero-padded rows make bounds
// uniform; trips = 37 per wave for ALL waves).

#define NT 256
#define H_STRIDE 68        // 65 + zero pad
#define X_STRIDE 84        // 80 + pad (rows 16B aligned)
#define W_STRIDE 164       // W_P + tau storage; banking stride 4 mod 32
#define W_P 14             // w[tau] at wr[W_P+tau]; valid tau in [0,128]; zeros outside
#define NSLOT 35           // frames f0-2 .. f0+32

__global__ void __launch_bounds__(NT)
fng_kernel(const float* __restrict__ Hg_, const float* __restrict__ Ng_,
           float* __restrict__ Og_) {
  __shared__ __align__(16) float sH[NSLOT * H_STRIDE];   //  9.52 KB
  __shared__ __align__(16) float sW[NSLOT * W_STRIDE];   // 22.96 KB
  __shared__ __align__(16) float sX[NSLOT * X_STRIDE];   // 11.76 KB  (total 44.2 KB -> 3 wg/CU)

  const int t  = threadIdx.x;
  const int bx = blockIdx.x;     // 0..124 (32 output-frames each)
  const int b  = blockIdx.y;     // 0..31
  const int f0 = bx * 32;
  const float TP = 6.28318530717958647692f / 129.f;

  // ---------------- P0: zero sW, stage H and x (slots f0-2 .. f0+32) ----------------
  {
    float4 z4 = {0.f, 0.f, 0.f, 0.f};
    for (int i = t; i < NSLOT * W_STRIDE / 4; i += NT) ((float4*)sW)[i] = z4;
    const float* Hg = Hg_ + (size_t)b * (4000 * 65);
    for (int i = t; i < NSLOT * H_STRIDE; i += NT) {
      int fi = i / H_STRIDE, kk = i - fi * H_STRIDE;
      int fr = f0 - 2 + fi;
      float v = 0.f;
      if (kk < 65 && fr >= 0 && fr < 4000) v = Hg[fr * 65 + kk];
      sH[i] = v;
    }
    const float* Ng = Ng_ + (size_t)b * 320000;
    for (int q = t; q < NSLOT * 21; q += NT) {       // 21 quads/row (20 data + 1 pad)
      int fi = q / 21, qm = q - fi * 21;
      int fr = f0 - 2 + fi;
      float4 v = {0.f, 0.f, 0.f, 0.f};
      if (qm < 20 && fr >= 0 && fr < 4000) {
        float4 r = *(const float4*)&Ng[fr * 80 + 4 * qm];
        v.x = r.x * 2.f - 1.f; v.y = r.y * 2.f - 1.f;
        v.z = r.z * 2.f - 1.f; v.w = r.w * 2.f - 1.f;
      }
      *(float4*)&sX[fi * X_STRIDE + 4 * qm] = v;
    }
  }
  __syncthreads();

  // ------- P1: windowed FIR via Chebyshev cos recurrence (8 chains/task) -------
  auto p1_task = [&](int slot, int dg) {
    int fr = f0 - 2 + slot;
    if (fr < 0 || fr >= 4000) return;                // row stays zero
    const float* hr = &sH[slot * H_STRIDE];
    float* wr = &sW[slot * W_STRIDE];
    float two_a[8], cc[8], cm[8], ac[8];
#pragma unroll
    for (int j = 0; j < 8; ++j) {
      float a = __cosf((float)(dg + 8 * j) * TP);
      two_a[j] = 2.f * a; cc[j] = 1.f; cm[j] = a; ac[j] = 0.f;
    }
    const float h0 = hr[0];
#pragma unroll 1
    for (int k = 0; k < 68; k += 4) {                // k=65..67 zero-padded
      float4 h4 = *(const float4*)&hr[k];
      const float hh[4] = {h4.x, h4.y, h4.z, h4.w};
#pragma unroll
      for (int mm = 0; mm < 4; ++mm)
#pragma unroll
        for (int j = 0; j < 8; ++j) {
          ac[j] = fmaf(hh[mm], cc[j], ac[j]);
          float cn = fmaf(two_a[j], cc[j], -cm[j]);
          cm[j] = cc[j]; cc[j] = cn;
        }
    }
#pragma unroll
    for (int j = 0; j < 8; ++j) {
      int d = dg + 8 * j;                            // 0..63
      float zp = (2.f * ac[j] - h0) * (1.f / 129.f);
      wr[W_P + 64 + d] = (0.5f - 0.5f * __cosf((float)(64 + d) * TP)) * zp;
      wr[W_P + 64 - d] = (0.5f - 0.5f * __cosf((float)(64 - d) * TP)) * zp;
    }
  };
  p1_task(t >> 3, t & 7);                            // slots 0..31
  if (t >= 232) p1_task(32 + ((t - 232) >> 3), (t - 232) & 7);  // slots 32..34 (wave 3)
  if (t >= 64 && t < 64 + NSLOT) {                   // d=64 chains on wave 1
    int slot = t - 64;
    int fr = f0 - 2 + slot;
    if (fr >= 0 && fr < 4000) {
      const float* hr = &sH[slot * H_STRIDE];
      float a = __cosf(64.f * TP);
      float a2 = 2.f * a, c_ = 1.f, cmv = a, s_ = 0.f;
#pragma unroll 1
      for (int k = 0; k < 68; k += 4) {
        float4 h4 = *(const float4*)&hr[k];
        s_ = fmaf(h4.x, c_, s_); { float cn = fmaf(a2, c_, -cmv); cmv = c_; c_ = cn; }
        s_ = fmaf(h4.y, c_, s_); { float cn = fmaf(a2, c_, -cmv); cmv = c_; c_ = cn; }
        s_ = fmaf(h4.z, c_, s_); { float cn = fmaf(a2, c_, -cmv); cmv = c_; c_ = cn; }
        s_ = fmaf(h4.w, c_, s_); { float cn = fmaf(a2, c_, -cmv); cmv = c_; c_ = cn; }
      }
      float zp = (2.f * s_ - hr[0]) * (1.f / 129.f);
      sW[slot * W_STRIDE + W_P + 128] =
          (0.5f - 0.5f * __cosf(128.f * TP)) * zp;   // tau=128; tau=0 is hann[0]=0
    }
  }
  __syncthreads();

  // ---------------- P2: gather convolution + direct stores ----------------
  {
    const int col = t & 31;
    const int pb  = t >> 5;
    const int e   = 64 + 10 * pb;
    const int qq  = (e >= 80) ? 1 : 0;
    const int D   = e - 80 * qq;                     // per half-wave uniform
    float acc[10];
#pragma unroll
    for (int i = 0; i < 10; ++i) acc[i] = 0.f;

#pragma unroll 1
    for (int g = 2; g >= -1; --g) {                  // source frame F - g
      const int dlt = D + 80 * g;
      int Qlo = (dlt - 131 + 3) >> 2; if (Qlo < 0) Qlo = 0;   // ceil((dlt-131)/4)
      int Qhi = (dlt + 9) >> 2;       if (Qhi > 19) Qhi = 19; // floor((dlt+9)/4)
      if (Qlo > Qhi) continue;
      const int slot = col + qq - g + 2;             // 0..34
      const float* wr = &sW[slot * W_STRIDE];
      const float* xr = &sX[slot * X_STRIDE];
      int wb = W_P + dlt - 4 * Qlo - 4;              // window base (even, >=0)
      float wv[16];
#pragma unroll
      for (int k = 0; k < 8; ++k) {
        float2 w2 = *(const float2*)&wr[wb + 2 * k];
        wv[2 * k] = w2.x; wv[2 * k + 1] = w2.y;
      }
#pragma unroll 2
      for (int Q = Qlo; Q <= Qhi; ++Q) {
        float4 x4 = *(const float4*)&xr[4 * Q];
        const float xv[4] = {x4.x, x4.y, x4.z, x4.w};
#pragma unroll
        for (int mm = 0; mm < 4; ++mm)
#pragma unroll
          for (int i = 0; i < 10; ++i)
            acc[i] = fmaf(xv[mm], wv[i - mm + 4], acc[i]);   // static idx in [1,13]
        // slide window down 4 (clamped; pad reads are zeros, never used on last trip)
        wb -= 4; int wc = (wb < 0) ? 0 : wb;
#pragma unroll
        for (int k = 15; k >= 4; --k) wv[k] = wv[k - 4];
        float2 wA = *(const float2*)&wr[wc];
        float2 wB = *(const float2*)&wr[wc + 2];
        wv[0] = wA.x; wv[1] = wA.y; wv[2] = wB.x; wv[3] = wB.y;
      }
    }

    // exactly-once writeout: u0 = 80*col + 10*pb (even -> float2 stores)
    float* Ob = Og_ + (size_t)b * 320000 + 2560 * bx + 80 * col + 10 * pb;
#pragma unroll
    for (int s = 0; s < 5; ++s) {
      float2 v; v.x = acc[2 * s]; v.y = acc[2 * s + 1];
      *(float2*)&Ob[2 * s] = v;
    }
  }
}

extern "C" void kernel_launch(void* const* d_in, const int* in_sizes, int n_in,
                              void* d_out, int out_size, void* d_ws, size_t ws_size,
                              hipStream_t stream) {
  const float* H     = (const float*)d_in[0];   // [32,4000,65] fp32
  const float* noise = (const float*)d_in[1];   // [32,4000,80] fp32
  float* out = (float*)d_out;                   // [32,320000] fp32
  (void)in_sizes; (void)n_in; (void)d_ws; (void)ws_size; (void)out_size;

  dim3 grid(125, 32, 1);
  fng_kernel<<<grid, NT, 0, stream>>>(H, noise, out);
}

// Round 5
// 176.972 us; speedup vs baseline: 5.3444x; 1.1329x over previous
//
#include <hip/hip_runtime.h>

// FilteredNoiseGenerator: B=32, t=4000, nbands=65, framesize=80, L_fir=129, L=208
// out[b,p] = sum_{f,m} x[b,f,m]*w[b,f,tau], tau = (p+64) - 80f - m in [0,128]
// w[f][n] = hann[n]*zp[f][|n-64|], zp[f][d] = (2*sum_k H[f][k]cos(2pi k d/129) - H[f][0])/129
//
// GATHER form (R4-proven): workgroup owns 2560 outputs (32 frames); thread owns
// 10 consecutive outputs. R5: sH/sX share one LDS region (noise parked in regs
// across P1) -> 4 wg/CU; W_STRIDE 166 (2-way banking = free); LDS cos table;
// Q-loop unroll(4) so the period-4 window rotation register-renames (no movs).

#define NT 256
#define H_STRIDE 68        // 65 + zero pad (4*17, 17 odd -> b128 starts spread)
#define X_STRIDE 84        // 80 + pad (4*21, 21 odd -> b128 starts spread)
#define W_STRIDE 166       // lane stride 166 = 6 mod 32, gcd 2 -> 2-way (free)
#define W_P 14             // w[tau] at wr[W_P+tau]; tau in [0,128]; zeros outside
#define NSLOT 35           // frames f0-2 .. f0+32
#define WTOT (NSLOT * W_STRIDE)       // 5810 (+2 pad for float4 zeroing)
#define UTOT (NSLOT * X_STRIDE)       // 2940 >= NSLOT*H_STRIDE = 2380

__global__ void __launch_bounds__(NT)
fng_kernel(const float* __restrict__ Hg_, const float* __restrict__ Ng_,
           float* __restrict__ Og_) {
  __shared__ __align__(16) float sW[WTOT + 2];   // 23,248 B
  __shared__ __align__(16) float sU[UTOT];       // 11,760 B: H during P1, x during P2
  __shared__ float cosT[132];                    //    528 B: cos(2pi n/129), n=0..128
  // total ~35.5 KB -> 4 wg/CU

  const int t  = threadIdx.x;
  const int bx = blockIdx.x;     // 0..124 (32 output-frames each)
  const int b  = blockIdx.y;     // 0..31
  const int f0 = bx * 32;
  const float TP = 6.28318530717958647692f / 129.f;

  // ---------------- P0: zero sW, cos table, H -> sU, noise -> regs ----------------
  float4 xq[3];                  // parked noise quads (raw; 0.5 -> transforms to 0)
  {
    float4 z4 = {0.f, 0.f, 0.f, 0.f};
    for (int i = t; i < (WTOT + 2) / 4; i += NT) ((float4*)sW)[i] = z4;
    if (t < 129) cosT[t] = __cosf((float)t * TP);
    const float* Hg = Hg_ + (size_t)b * (4000 * 65);
    for (int i = t; i < NSLOT * H_STRIDE; i += NT) {
      int fi = i / H_STRIDE, kk = i - fi * H_STRIDE;
      int fr = f0 - 2 + fi;
      float v = 0.f;
      if (kk < 65 && fr >= 0 && fr < 4000) v = Hg[fr * 65 + kk];
      sU[i] = v;
    }
    const float* Ng = Ng_ + (size_t)b * 320000;
#pragma unroll
    for (int j = 0; j < 3; ++j) {
      int q = t + 256 * j;
      float4 v = {0.5f, 0.5f, 0.5f, 0.5f};      // 2*0.5-1 = 0 for OOB rows
      if (q < NSLOT * 21) {
        int fi = q / 21, qm = q - fi * 21;
        int fr = f0 - 2 + fi;
        if (qm < 20 && fr >= 0 && fr < 4000)
          v = *(const float4*)&Ng[(size_t)fr * 80 + 4 * qm];
      }
      xq[j] = v;
    }
  }
  __syncthreads();

  // ------- P1: windowed FIR via Chebyshev cos recurrence (8 chains/task) -------
  auto p1_task = [&](int slot, int dg) {
    int fr = f0 - 2 + slot;
    if (fr < 0 || fr >= 4000) return;            // row stays zero
    const float* hr = &sU[slot * H_STRIDE];
    float* wr = &sW[slot * W_STRIDE];
    float two_a[8], cc[8], cm[8], ac[8];
#pragma unroll
    for (int j = 0; j < 8; ++j) {
      float a = cosT[dg + 8 * j];
      two_a[j] = 2.f * a; cc[j] = 1.f; cm[j] = a; ac[j] = 0.f;
    }
    const float h0 = hr[0];
#pragma unroll 1
    for (int k = 0; k < 68; k += 4) {            // k=65..67 zero-padded
      float4 h4 = *(const float4*)&hr[k];
      const float hh[4] = {h4.x, h4.y, h4.z, h4.w};
#pragma unroll
      for (int mm = 0; mm < 4; ++mm)
#pragma unroll
        for (int j = 0; j < 8; ++j) {
          ac[j] = fmaf(hh[mm], cc[j], ac[j]);
          float cn = fmaf(two_a[j], cc[j], -cm[j]);
          cm[j] = cc[j]; cc[j] = cn;
        }
    }
#pragma unroll
    for (int j = 0; j < 8; ++j) {
      int d = dg + 8 * j;                        // 0..63
      float zp = (2.f * ac[j] - h0) * (1.f / 129.f);
      wr[W_P + 64 + d] = (0.5f - 0.5f * cosT[64 + d]) * zp;
      wr[W_P + 64 - d] = (0.5f - 0.5f * cosT[64 - d]) * zp;
    }
  };
  p1_task(t >> 3, t & 7);                        // slots 0..31
  if (t >= 232) p1_task(32 + ((t - 232) >> 3), (t - 232) & 7);  // slots 32..34
  if (t >= 64 && t < 64 + NSLOT) {               // d=64 chains on wave 1
    int slot = t - 64;
    int fr = f0 - 2 + slot;
    if (fr >= 0 && fr < 4000) {
      const float* hr = &sU[slot * H_STRIDE];
      float a = cosT[64];
      float a2 = 2.f * a, c_ = 1.f, cmv = a, s_ = 0.f;
#pragma unroll 1
      for (int k = 0; k < 68; k += 4) {
        float4 h4 = *(const float4*)&hr[k];
        s_ = fmaf(h4.x, c_, s_); { float cn = fmaf(a2, c_, -cmv); cmv = c_; c_ = cn; }
        s_ = fmaf(h4.y, c_, s_); { float cn = fmaf(a2, c_, -cmv); cmv = c_; c_ = cn; }
        s_ = fmaf(h4.z, c_, s_); { float cn = fmaf(a2, c_, -cmv); cmv = c_; c_ = cn; }
        s_ = fmaf(h4.w, c_, s_); { float cn = fmaf(a2, c_, -cmv); cmv = c_; c_ = cn; }
      }
      float zp = (2.f * s_ - hr[0]) * (1.f / 129.f);
      sW[slot * W_STRIDE + W_P + 128] = (0.5f - 0.5f * cosT[128]) * zp;
      // tau=0 is hann[0]=0: covered by zero-init.
    }
  }
  __syncthreads();

  // ---------------- P1.5: park noise into sU (overwrites H region) ----------------
#pragma unroll
  for (int j = 0; j < 3; ++j) {
    int q = t + 256 * j;
    if (q < NSLOT * 21) {
      int fi = q / 21, qm = q - fi * 21;
      if (qm < 20) {                             // pad quad qm=20 never read by P2
        float4 v = xq[j], o;
        o.x = 2.f * v.x - 1.f; o.y = 2.f * v.y - 1.f;
        o.z = 2.f * v.z - 1.f; o.w = 2.f * v.w - 1.f;
        *(float4*)&sU[fi * X_STRIDE + 4 * qm] = o;
      }
    }
  }
  __syncthreads();

  // ---------------- P2: gather convolution + direct stores ----------------
  {
    const int col = t & 31;
    const int pb  = t >> 5;
    const int e   = 64 + 10 * pb;
    const int qq  = (e >= 80) ? 1 : 0;
    const int D   = e - 80 * qq;                 // per half-wave uniform
    float acc[10];
#pragma unroll
    for (int i = 0; i < 10; ++i) acc[i] = 0.f;

#pragma unroll 1
    for (int g = 2; g >= -1; --g) {              // source frame F - g
      const int dlt = D + 80 * g;
      int Qlo = (dlt - 131 + 3) >> 2; if (Qlo < 0) Qlo = 0;   // ceil((dlt-131)/4)
      int Qhi = (dlt + 9) >> 2;       if (Qhi > 19) Qhi = 19; // floor((dlt+9)/4)
      if (Qlo > Qhi) continue;
      const int slot = col + qq - g + 2;         // 0..34
      const float* wr = &sW[slot * W_STRIDE];
      const float* xr = &sU[slot * X_STRIDE];
      int wb = W_P + dlt - 4 * Qlo - 4;          // window base (even)
      float wv[16];
#pragma unroll
      for (int k = 0; k < 8; ++k) {
        float2 w2 = *(const float2*)&wr[wb + 2 * k];
        wv[2 * k] = w2.x; wv[2 * k + 1] = w2.y;
      }
#pragma unroll 4                                 // period-4 rotation -> renamed, no movs
      for (int Q = Qlo; Q <= Qhi; ++Q) {
        float4 x4 = *(const float4*)&xr[4 * Q];
        const float xv[4] = {x4.x, x4.y, x4.z, x4.w};
#pragma unroll
        for (int mm = 0; mm < 4; ++mm)
#pragma unroll
          for (int i = 0; i < 10; ++i)
            acc[i] = fmaf(xv[mm], wv[i - mm + 4], acc[i]);   // static idx in [1,13]
        // slide window down 4 (clamped; pad zeros, unused on last trip)
        wb -= 4; int wc = (wb < 0) ? 0 : wb;
#pragma unroll
        for (int k = 15; k >= 4; --k) wv[k] = wv[k - 4];
        float2 wA = *(const float2*)&wr[wc];
        float2 wB = *(const float2*)&wr[wc + 2];
        wv[0] = wA.x; wv[1] = wA.y; wv[2] = wB.x; wv[3] = wB.y;
      }
    }

    // exactly-once writeout: u0 = 80*col + 10*pb (even -> float2 stores)
    float* Ob = Og_ + (size_t)b * 320000 + 2560 * bx + 80 * col + 10 * pb;
#pragma unroll
    for (int s = 0; s < 5; ++s) {
      float2 v; v.x = acc[2 * s]; v.y = acc[2 * s + 1];
      *(float2*)&Ob[2 * s] = v;
    }
  }
}

extern "C" void kernel_launch(void* const* d_in, const int* in_sizes, int n_in,
                              void* d_out, int out_size, void* d_ws, size_t ws_size,
                              hipStream_t stream) {
  const float* H     = (const float*)d_in[0];   // [32,4000,65] fp32
  const float* noise = (const float*)d_in[1];   // [32,4000,80] fp32
  float* out = (float*)d_out;                   // [32,320000] fp32
  (void)in_sizes; (void)n_in; (void)d_ws; (void)ws_size; (void)out_size;

  dim3 grid(125, 32, 1);
  fng_kernel<<<grid, NT, 0, stream>>>(H, noise, out);
}